// Round 1
// baseline (4240.055 us; speedup 1.0000x reference)
//
#include <hip/hip_runtime.h>
#include <math.h>

typedef __bf16 bf16_t;
typedef __bf16 bf16x8 __attribute__((ext_vector_type(8)));
typedef float f32x4 __attribute__((ext_vector_type(4)));

#define HID 2048
#define NBATCH 16
#define SEQLEN 512
#define MTOT (NBATCH * SEQLEN)
#define NBLK 64
#define RTHREADS 512
#define LN_EPS 1e-5f

// ================= GEMM: inp = x @ Wi^T + b  -> d_out (fp32) =================
// A = x [8192][2048] fp32, B = Wi [2048][2048] fp32 (row o, contiguous h).
// bf16 MFMA with fp32 accumulate. Reg-staged LDS (convert fp32->bf16 on the fly).
__global__ __launch_bounds__(256) void gemm_proj(
    const float* __restrict__ X,
    const float* __restrict__ Wi,
    const float* __restrict__ bias,
    float* __restrict__ C,
    int* __restrict__ bar)
{
    __shared__ bf16_t lA[128 * 32];
    __shared__ bf16_t lB[128 * 32];
    const int tid = threadIdx.x;
    if (tid == 0 && blockIdx.x == 0 && blockIdx.y == 0) { bar[0] = 0; bar[1] = 0; }
    const int lane = tid & 63;
    const int wv = tid >> 6;
    const int bn = blockIdx.x * 128;
    const int bm = blockIdx.y * 128;
    const int wr = (wv >> 1) * 64;
    const int wc = (wv & 1) * 64;

    f32x4 zero = {0.f, 0.f, 0.f, 0.f};
    f32x4 acc[4][4];
#pragma unroll
    for (int i = 0; i < 4; ++i)
#pragma unroll
        for (int j = 0; j < 4; ++j) acc[i][j] = zero;

    for (int k0 = 0; k0 < HID; k0 += 32) {
        __syncthreads();
#pragma unroll
        for (int c = 0; c < 2; ++c) {
            const int chunk = c * 256 + tid;      // 0..511
            const int row = chunk >> 2;           // 0..127
            const int kp = (chunk & 3) ^ (row & 3); // XOR-swizzled source chunk
            {
                const float* s = X + (size_t)(bm + row) * HID + k0 + kp * 8;
                float4 a0 = *(const float4*)s;
                float4 a1 = *(const float4*)(s + 4);
                bf16x8 v;
                v[0] = (bf16_t)a0.x; v[1] = (bf16_t)a0.y; v[2] = (bf16_t)a0.z; v[3] = (bf16_t)a0.w;
                v[4] = (bf16_t)a1.x; v[5] = (bf16_t)a1.y; v[6] = (bf16_t)a1.z; v[7] = (bf16_t)a1.w;
                *(bf16x8*)(lA + chunk * 8) = v;
            }
            {
                const float* s = Wi + (size_t)(bn + row) * HID + k0 + kp * 8;
                float4 a0 = *(const float4*)s;
                float4 a1 = *(const float4*)(s + 4);
                bf16x8 v;
                v[0] = (bf16_t)a0.x; v[1] = (bf16_t)a0.y; v[2] = (bf16_t)a0.z; v[3] = (bf16_t)a0.w;
                v[4] = (bf16_t)a1.x; v[5] = (bf16_t)a1.y; v[6] = (bf16_t)a1.z; v[7] = (bf16_t)a1.w;
                *(bf16x8*)(lB + chunk * 8) = v;
            }
        }
        __syncthreads();

        bf16x8 af[4], bfr[4];
#pragma unroll
        for (int i = 0; i < 4; ++i) {
            const int row = wr + i * 16 + (lane & 15);
            const int ck = (lane >> 4) ^ (row & 3);
            af[i] = *(const bf16x8*)(lA + row * 32 + ck * 8);
        }
#pragma unroll
        for (int j = 0; j < 4; ++j) {
            const int row = wc + j * 16 + (lane & 15);
            const int ck = (lane >> 4) ^ (row & 3);
            bfr[j] = *(const bf16x8*)(lB + row * 32 + ck * 8);
        }
#pragma unroll
        for (int i = 0; i < 4; ++i)
#pragma unroll
            for (int j = 0; j < 4; ++j)
                acc[i][j] = __builtin_amdgcn_mfma_f32_16x16x32_bf16(af[i], bfr[j], acc[i][j], 0, 0, 0);
    }

#pragma unroll
    for (int j = 0; j < 4; ++j) {
        const int col = bn + wc + j * 16 + (lane & 15);
        const float bv = bias[col];
#pragma unroll
        for (int i = 0; i < 4; ++i) {
#pragma unroll
            for (int r = 0; r < 4; ++r) {
                const int row = bm + wr + i * 16 + (lane >> 4) * 4 + r;
                C[(size_t)row * HID + col] = acc[i][j][r] + bv;
            }
        }
    }
}

// ================= Persistent recurrent kernel =================
// 64 blocks x 512 threads. Block owns 32 output cols; 8 waves = 2 col-tiles x 4 K-quarters.
// Wm bf16 MFMA B-fragments pinned in VGPRs (16 frags/wave). Grid barrier per step.
__device__ __forceinline__ void grid_barrier(int* __restrict__ bar, int target)
{
    __syncthreads();
    if (threadIdx.x == 0) {
        __threadfence();  // agent-scope release of this block's state/out stores
        __hip_atomic_fetch_add(&bar[0], 1, __ATOMIC_RELEASE, __HIP_MEMORY_SCOPE_AGENT);
        while (__hip_atomic_load(&bar[0], __ATOMIC_ACQUIRE, __HIP_MEMORY_SCOPE_AGENT) < target) {
            __builtin_amdgcn_s_sleep(1);
        }
    }
    __syncthreads();
}

__global__ __launch_bounds__(RTHREADS, 1) void recurrent(
    const float* __restrict__ Wr,
    const float* __restrict__ mask,
    const float* __restrict__ tau,
    float* __restrict__ io,      // d_out: holds inp (read rows t+1) -> states (write row t)
    bf16_t* __restrict__ st0,
    bf16_t* __restrict__ st1,
    int* __restrict__ bar)
{
    const int tid = threadIdx.x;
    const int lane = tid & 63;
    const int wv = tid >> 6;          // 0..7
    const int ct = wv >> 2;           // col-tile 0..1
    const int kq = wv & 3;            // K-quarter 0..3
    const int colbase = blockIdx.x * 32;

    __shared__ float red[2048];       // 8 waves x 256 partials

    // ---- preload masked recurrent weights as MFMA B-fragments (VGPR-resident) ----
    bf16x8 wf[16];
    {
        const int gc = colbase + ct * 16 + (lane & 15);
        const int kb = kq * 512 + (lane >> 4) * 8;
#pragma unroll
        for (int ks = 0; ks < 16; ++ks) {
            const size_t off = (size_t)gc * HID + kb + ks * 32;
            float4 a0 = *(const float4*)(Wr + off);
            float4 a1 = *(const float4*)(Wr + off + 4);
            float4 m0 = *(const float4*)(mask + off);
            float4 m1 = *(const float4*)(mask + off + 4);
            bf16x8 v;
            v[0] = (bf16_t)(a0.x * m0.x); v[1] = (bf16_t)(a0.y * m0.y);
            v[2] = (bf16_t)(a0.z * m0.z); v[3] = (bf16_t)(a0.w * m0.w);
            v[4] = (bf16_t)(a1.x * m1.x); v[5] = (bf16_t)(a1.y * m1.y);
            v[6] = (bf16_t)(a1.z * m1.z); v[7] = (bf16_t)(a1.w * m1.w);
            wf[ks] = v;
        }
    }

    // update-thread mapping: 512 threads <-> 16 batches x 32 cols
    const int ub = tid >> 5;
    const int uc = tid & 31;
    const int ugc = colbase + uc;
    float alpha;
    {
        float tv = tau[ugc];
        tv = fminf(fmaxf(tv, 1.0f), 20.0f);
        alpha = fminf(fmaxf(0.5f / tv, 0.0f), 1.0f);
    }

    // zero initial bf16 state slice; fp32 master state in register
    st0[(size_t)ub * HID + ugc] = (bf16_t)0.f;
    float s_old = 0.f;
    float cur_inp = io[(size_t)ub * (SEQLEN * HID) + ugc];

    int nbar = 0;
    grid_barrier(bar, ++nbar * NBLK);   // st0 zeros visible everywhere

    const bf16_t* cur = st0;
    bf16_t* nxt = st1;
    const int arow = lane & 15;                 // batch row of A fragment
    const int akb = kq * 512 + (lane >> 4) * 8; // k offset of A fragment
    const int rb = (uc >> 4) * 1024 + ub * 16 + (uc & 15);

    for (int t = 0; t < SEQLEN; ++t) {
        // prefetch next timestep's input (row t+1 of io; never conflicts with row-t writes)
        const int tn = (t < SEQLEN - 1) ? (t + 1) : t;
        const float next_inp = io[(size_t)ub * (SEQLEN * HID) + (size_t)tn * HID + ugc];

        // ---- matvec partial: state[16,512-slice] @ Wm_slice -> 16x16 tile ----
        bf16x8 af[16];
        const bf16_t* abase = cur + (size_t)arow * HID + akb;
#pragma unroll
        for (int ks = 0; ks < 16; ++ks)
            af[ks] = *(const bf16x8*)(abase + ks * 32);
        f32x4 acc = {0.f, 0.f, 0.f, 0.f};
#pragma unroll
        for (int ks = 0; ks < 16; ++ks)
            acc = __builtin_amdgcn_mfma_f32_16x16x32_bf16(af[ks], wf[ks], acc, 0, 0, 0);

        // ---- cross-wave K reduction via LDS ----
        const int wbase = wv * 256 + (lane >> 4) * 64 + (lane & 15);
        red[wbase]      = acc[0];
        red[wbase + 16] = acc[1];
        red[wbase + 32] = acc[2];
        red[wbase + 48] = acc[3];
        __syncthreads();
        const float rec = red[rb] + red[rb + 256] + red[rb + 512] + red[rb + 768];

        // ---- fused update: tanh + EMA + clip ----
        float z = cur_inp + rec;
        z = fminf(fmaxf(z, -15.f), 15.f);
        const float e = __expf(2.0f * z);
        const float tgt = (e - 1.0f) / (e + 1.0f);
        float sn = s_old + alpha * (tgt - s_old);
        sn = fminf(fmaxf(sn, -1.0f), 1.0f);

        io[(size_t)ub * (SEQLEN * HID) + (size_t)t * HID + ugc] = sn;   // pre-LN output
        nxt[(size_t)ub * HID + ugc] = (bf16_t)sn;                       // next matvec input

        s_old = sn;
        cur_inp = next_inp;

        if (t != SEQLEN - 1) grid_barrier(bar, ++nbar * NBLK);

        bf16_t* tmp = (bf16_t*)cur; cur = nxt; nxt = tmp;
    }
}

// ================= LayerNorm (in-place on d_out) =================
__global__ __launch_bounds__(256) void ln_kernel(
    float* __restrict__ io,
    const float* __restrict__ gamma,
    const float* __restrict__ beta)
{
    const size_t row = blockIdx.x;
    float* p = io + row * HID;
    const int tid = threadIdx.x;
    float4 v0 = *(const float4*)(p + tid * 4);
    float4 v1 = *(const float4*)(p + 1024 + tid * 4);
    float s  = v0.x + v0.y + v0.z + v0.w + v1.x + v1.y + v1.z + v1.w;
    float ss = v0.x * v0.x + v0.y * v0.y + v0.z * v0.z + v0.w * v0.w
             + v1.x * v1.x + v1.y * v1.y + v1.z * v1.z + v1.w * v1.w;
#pragma unroll
    for (int off = 32; off > 0; off >>= 1) {
        s  += __shfl_down(s, off, 64);
        ss += __shfl_down(ss, off, 64);
    }
    __shared__ float rs[4], rss[4];
    if ((tid & 63) == 0) { rs[tid >> 6] = s; rss[tid >> 6] = ss; }
    __syncthreads();
    s  = rs[0] + rs[1] + rs[2] + rs[3];
    ss = rss[0] + rss[1] + rss[2] + rss[3];
    const float mu = s * (1.f / HID);
    const float var = ss * (1.f / HID) - mu * mu;
    const float inv = rsqrtf(var + LN_EPS);
    const int c0 = tid * 4, c1 = 1024 + tid * 4;
    float4 g0 = *(const float4*)(gamma + c0);
    float4 g1 = *(const float4*)(gamma + c1);
    float4 b0 = *(const float4*)(beta + c0);
    float4 b1 = *(const float4*)(beta + c1);
    float4 o0, o1;
    o0.x = (v0.x - mu) * inv * g0.x + b0.x;
    o0.y = (v0.y - mu) * inv * g0.y + b0.y;
    o0.z = (v0.z - mu) * inv * g0.z + b0.z;
    o0.w = (v0.w - mu) * inv * g0.w + b0.w;
    o1.x = (v1.x - mu) * inv * g1.x + b1.x;
    o1.y = (v1.y - mu) * inv * g1.y + b1.y;
    o1.z = (v1.z - mu) * inv * g1.z + b1.z;
    o1.w = (v1.w - mu) * inv * g1.w + b1.w;
    *(float4*)(p + tid * 4) = o0;
    *(float4*)(p + 1024 + tid * 4) = o1;
}

extern "C" void kernel_launch(void* const* d_in, const int* in_sizes, int n_in,
                              void* d_out, int out_size, void* d_ws, size_t ws_size,
                              hipStream_t stream)
{
    const float* x     = (const float*)d_in[0];
    const float* Wi    = (const float*)d_in[1];
    const float* bias  = (const float*)d_in[2];
    const float* Wr    = (const float*)d_in[3];
    const float* mask  = (const float*)d_in[4];
    const float* tau   = (const float*)d_in[5];
    const float* gamma = (const float*)d_in[6];
    const float* beta  = (const float*)d_in[7];
    float* out = (float*)d_out;

    bf16_t* st0 = (bf16_t*)d_ws;
    bf16_t* st1 = st0 + (size_t)NBATCH * HID;
    int* bar    = (int*)(st1 + (size_t)NBATCH * HID);

    // 1) input projection -> d_out rows hold inp[b,t,:] (fp32), also inits barrier
    gemm_proj<<<dim3(16, 64), 256, 0, stream>>>(x, Wi, bias, out, bar);
    // 2) persistent recurrence: overwrites d_out rows with pre-LN states
    recurrent<<<NBLK, RTHREADS, 0, stream>>>(Wr, mask, tau, out, st0, st1, bar);
    // 3) layernorm in-place
    ln_kernel<<<MTOT, 256, 0, stream>>>(out, gamma, beta);
}

// Round 2
// 4032.114 us; speedup vs baseline: 1.0516x; 1.0516x over previous
//
#include <hip/hip_runtime.h>
#include <math.h>

typedef __bf16 bf16_t;
typedef __bf16 bf16x8 __attribute__((ext_vector_type(8)));
typedef float f32x4 __attribute__((ext_vector_type(4)));

#define HID 2048
#define NBATCH 16
#define SEQLEN 512
#define MTOT (NBATCH * SEQLEN)
#define NBLK 64
#define RTHREADS 512
#define LN_EPS 1e-5f
#define FLAG_STRIDE 32   // 128B per flag line

// ================= GEMM: inp = x @ Wi^T + b  -> d_out (fp32) =================
__global__ __launch_bounds__(256) void gemm_proj(
    const float* __restrict__ X,
    const float* __restrict__ Wi,
    const float* __restrict__ bias,
    float* __restrict__ C,
    int* __restrict__ flags)
{
    __shared__ bf16_t lA[128 * 32];
    __shared__ bf16_t lB[128 * 32];
    const int tid = threadIdx.x;
    if (blockIdx.x == 0 && blockIdx.y == 0) {
        // zero the distributed barrier flags (64 lines x 32 ints)
        for (int i = tid; i < NBLK * FLAG_STRIDE; i += 256) flags[i] = 0;
    }
    const int lane = tid & 63;
    const int wv = tid >> 6;
    const int bn = blockIdx.x * 128;
    const int bm = blockIdx.y * 128;
    const int wr = (wv >> 1) * 64;
    const int wc = (wv & 1) * 64;

    f32x4 zero = {0.f, 0.f, 0.f, 0.f};
    f32x4 acc[4][4];
#pragma unroll
    for (int i = 0; i < 4; ++i)
#pragma unroll
        for (int j = 0; j < 4; ++j) acc[i][j] = zero;

    for (int k0 = 0; k0 < HID; k0 += 32) {
        __syncthreads();
#pragma unroll
        for (int c = 0; c < 2; ++c) {
            const int chunk = c * 256 + tid;      // 0..511
            const int row = chunk >> 2;           // 0..127
            const int kp = (chunk & 3) ^ (row & 3); // XOR-swizzled source chunk
            {
                const float* s = X + (size_t)(bm + row) * HID + k0 + kp * 8;
                float4 a0 = *(const float4*)s;
                float4 a1 = *(const float4*)(s + 4);
                bf16x8 v;
                v[0] = (bf16_t)a0.x; v[1] = (bf16_t)a0.y; v[2] = (bf16_t)a0.z; v[3] = (bf16_t)a0.w;
                v[4] = (bf16_t)a1.x; v[5] = (bf16_t)a1.y; v[6] = (bf16_t)a1.z; v[7] = (bf16_t)a1.w;
                *(bf16x8*)(lA + chunk * 8) = v;
            }
            {
                const float* s = Wi + (size_t)(bn + row) * HID + k0 + kp * 8;
                float4 a0 = *(const float4*)s;
                float4 a1 = *(const float4*)(s + 4);
                bf16x8 v;
                v[0] = (bf16_t)a0.x; v[1] = (bf16_t)a0.y; v[2] = (bf16_t)a0.z; v[3] = (bf16_t)a0.w;
                v[4] = (bf16_t)a1.x; v[5] = (bf16_t)a1.y; v[6] = (bf16_t)a1.z; v[7] = (bf16_t)a1.w;
                *(bf16x8*)(lB + chunk * 8) = v;
            }
        }
        __syncthreads();

        bf16x8 af[4], bfr[4];
#pragma unroll
        for (int i = 0; i < 4; ++i) {
            const int row = wr + i * 16 + (lane & 15);
            const int ck = (lane >> 4) ^ (row & 3);
            af[i] = *(const bf16x8*)(lA + row * 32 + ck * 8);
        }
#pragma unroll
        for (int j = 0; j < 4; ++j) {
            const int row = wc + j * 16 + (lane & 15);
            const int ck = (lane >> 4) ^ (row & 3);
            bfr[j] = *(const bf16x8*)(lB + row * 32 + ck * 8);
        }
#pragma unroll
        for (int i = 0; i < 4; ++i)
#pragma unroll
            for (int j = 0; j < 4; ++j)
                acc[i][j] = __builtin_amdgcn_mfma_f32_16x16x32_bf16(af[i], bfr[j], acc[i][j], 0, 0, 0);
    }

#pragma unroll
    for (int j = 0; j < 4; ++j) {
        const int col = bn + wc + j * 16 + (lane & 15);
        const float bv = bias[col];
#pragma unroll
        for (int i = 0; i < 4; ++i) {
#pragma unroll
            for (int r = 0; r < 4; ++r) {
                const int row = bm + wr + i * 16 + (lane >> 4) * 4 + r;
                C[(size_t)row * HID + col] = acc[i][j][r] + bv;
            }
        }
    }
}

// ================= Distributed-flag grid barrier =================
// Each block release-stores step# to its OWN 128B line (no RMW contention).
// Wave 0 polls all 64 flags with 64 parallel relaxed lane-loads + ballot.
__device__ __forceinline__ void grid_barrier(int* __restrict__ flags, int tgt)
{
    __syncthreads();   // all waves' stores drained to L2 (vmcnt 0 before s_barrier)
    const int tid = threadIdx.x;
    if (tid < 64) {
        if (tid == 0) {
            // agent-release: writes back dirty L2 (covers whole block's stores), then store
            __hip_atomic_store(flags + (int)blockIdx.x * FLAG_STRIDE, tgt,
                               __ATOMIC_RELEASE, __HIP_MEMORY_SCOPE_AGENT);
        }
        int v;
        do {
            v = __hip_atomic_load(flags + tid * FLAG_STRIDE,
                                  __ATOMIC_RELAXED, __HIP_MEMORY_SCOPE_AGENT);
        } while (__ballot(v < tgt) != 0ull);
        __threadfence();   // acquire: invalidate L1/L2 before anyone reads state
    }
    __syncthreads();
}

// ================= Persistent recurrent kernel =================
__global__ __launch_bounds__(RTHREADS, 1) void recurrent(
    const float* __restrict__ Wr,
    const float* __restrict__ mask,
    const float* __restrict__ tau,
    float* __restrict__ io,      // d_out: holds inp (read rows t+1) -> states (write row t)
    bf16_t* __restrict__ st0,
    bf16_t* __restrict__ st1,
    int* __restrict__ flags)
{
    const int tid = threadIdx.x;
    const int lane = tid & 63;
    const int wv = tid >> 6;          // 0..7
    const int ct = wv >> 2;           // col-tile 0..1
    const int kq = wv & 3;            // K-quarter 0..3
    const int colbase = blockIdx.x * 32;

    __shared__ float red[2048];       // 8 waves x 256 partials

    // ---- preload masked recurrent weights as MFMA B-fragments (VGPR-resident) ----
    bf16x8 wf[16];
    {
        const int gc = colbase + ct * 16 + (lane & 15);
        const int kb = kq * 512 + (lane >> 4) * 8;
#pragma unroll
        for (int ks = 0; ks < 16; ++ks) {
            const size_t off = (size_t)gc * HID + kb + ks * 32;
            float4 a0 = *(const float4*)(Wr + off);
            float4 a1 = *(const float4*)(Wr + off + 4);
            float4 m0 = *(const float4*)(mask + off);
            float4 m1 = *(const float4*)(mask + off + 4);
            bf16x8 v;
            v[0] = (bf16_t)(a0.x * m0.x); v[1] = (bf16_t)(a0.y * m0.y);
            v[2] = (bf16_t)(a0.z * m0.z); v[3] = (bf16_t)(a0.w * m0.w);
            v[4] = (bf16_t)(a1.x * m1.x); v[5] = (bf16_t)(a1.y * m1.y);
            v[6] = (bf16_t)(a1.z * m1.z); v[7] = (bf16_t)(a1.w * m1.w);
            wf[ks] = v;
        }
    }

    // update-thread mapping: 512 threads <-> 16 batches x 32 cols
    const int ub = tid >> 5;
    const int uc = tid & 31;
    const int ugc = colbase + uc;
    float alpha;
    {
        float tv = tau[ugc];
        tv = fminf(fmaxf(tv, 1.0f), 20.0f);
        alpha = fminf(fmaxf(0.5f / tv, 0.0f), 1.0f);
    }

    // zero initial bf16 state slice; fp32 master state in register
    st0[(size_t)ub * HID + ugc] = (bf16_t)0.f;
    float s_old = 0.f;
    float cur_inp = io[(size_t)ub * (SEQLEN * HID) + ugc];

    int nbar = 0;
    grid_barrier(flags, ++nbar);   // st0 zeros visible everywhere

    const bf16_t* cur = st0;
    bf16_t* nxt = st1;
    const int arow = lane & 15;                 // batch row of A fragment
    const int akb = kq * 512 + (lane >> 4) * 8; // k offset of A fragment
    const int rb = (uc >> 4) * 1024 + ub * 16 + (uc & 15);

    for (int t = 0; t < SEQLEN; ++t) {
        // prefetch next timestep's input (row t+1 of io; never conflicts with row-t writes)
        const int tn = (t < SEQLEN - 1) ? (t + 1) : t;
        const float next_inp = io[(size_t)ub * (SEQLEN * HID) + (size_t)tn * HID + ugc];

        // ---- matvec partial: state[16,512-slice] @ Wm_slice -> 16x16 tile ----
        bf16x8 af[16];
        const bf16_t* abase = cur + (size_t)arow * HID + akb;
#pragma unroll
        for (int ks = 0; ks < 16; ++ks)
            af[ks] = *(const bf16x8*)(abase + ks * 32);
        // 4 accumulators to shorten the dependent MFMA chain
        f32x4 a0 = {0.f,0.f,0.f,0.f}, a1v = {0.f,0.f,0.f,0.f};
        f32x4 a2 = {0.f,0.f,0.f,0.f}, a3 = {0.f,0.f,0.f,0.f};
#pragma unroll
        for (int ks = 0; ks < 16; ks += 4) {
            a0  = __builtin_amdgcn_mfma_f32_16x16x32_bf16(af[ks],     wf[ks],     a0,  0, 0, 0);
            a1v = __builtin_amdgcn_mfma_f32_16x16x32_bf16(af[ks + 1], wf[ks + 1], a1v, 0, 0, 0);
            a2  = __builtin_amdgcn_mfma_f32_16x16x32_bf16(af[ks + 2], wf[ks + 2], a2,  0, 0, 0);
            a3  = __builtin_amdgcn_mfma_f32_16x16x32_bf16(af[ks + 3], wf[ks + 3], a3,  0, 0, 0);
        }
        f32x4 acc = (a0 + a1v) + (a2 + a3);

        // ---- cross-wave K reduction via LDS ----
        const int wbase = wv * 256 + (lane >> 4) * 64 + (lane & 15);
        red[wbase]      = acc[0];
        red[wbase + 16] = acc[1];
        red[wbase + 32] = acc[2];
        red[wbase + 48] = acc[3];
        __syncthreads();
        const float rec = red[rb] + red[rb + 256] + red[rb + 512] + red[rb + 768];

        // ---- fused update: tanh + EMA + clip ----
        float z = cur_inp + rec;
        z = fminf(fmaxf(z, -15.f), 15.f);
        const float e = __expf(2.0f * z);
        const float tgt = (e - 1.0f) / (e + 1.0f);
        float sn = s_old + alpha * (tgt - s_old);
        sn = fminf(fmaxf(sn, -1.0f), 1.0f);

        io[(size_t)ub * (SEQLEN * HID) + (size_t)t * HID + ugc] = sn;   // pre-LN output
        nxt[(size_t)ub * HID + ugc] = (bf16_t)sn;                       // next matvec input

        s_old = sn;
        cur_inp = next_inp;

        if (t != SEQLEN - 1) grid_barrier(flags, ++nbar);

        bf16_t* tmp = (bf16_t*)cur; cur = nxt; nxt = tmp;
    }
}

// ================= LayerNorm (in-place on d_out) =================
__global__ __launch_bounds__(256) void ln_kernel(
    float* __restrict__ io,
    const float* __restrict__ gamma,
    const float* __restrict__ beta)
{
    const size_t row = blockIdx.x;
    float* p = io + row * HID;
    const int tid = threadIdx.x;
    float4 v0 = *(const float4*)(p + tid * 4);
    float4 v1 = *(const float4*)(p + 1024 + tid * 4);
    float s  = v0.x + v0.y + v0.z + v0.w + v1.x + v1.y + v1.z + v1.w;
    float ss = v0.x * v0.x + v0.y * v0.y + v0.z * v0.z + v0.w * v0.w
             + v1.x * v1.x + v1.y * v1.y + v1.z * v1.z + v1.w * v1.w;
#pragma unroll
    for (int off = 32; off > 0; off >>= 1) {
        s  += __shfl_down(s, off, 64);
        ss += __shfl_down(ss, off, 64);
    }
    __shared__ float rs[4], rss[4];
    if ((tid & 63) == 0) { rs[tid >> 6] = s; rss[tid >> 6] = ss; }
    __syncthreads();
    s  = rs[0] + rs[1] + rs[2] + rs[3];
    ss = rss[0] + rss[1] + rss[2] + rss[3];
    const float mu = s * (1.f / HID);
    const float var = ss * (1.f / HID) - mu * mu;
    const float inv = rsqrtf(var + LN_EPS);
    const int c0 = tid * 4, c1 = 1024 + tid * 4;
    float4 g0 = *(const float4*)(gamma + c0);
    float4 g1 = *(const float4*)(gamma + c1);
    float4 b0 = *(const float4*)(beta + c0);
    float4 b1 = *(const float4*)(beta + c1);
    float4 o0, o1;
    o0.x = (v0.x - mu) * inv * g0.x + b0.x;
    o0.y = (v0.y - mu) * inv * g0.y + b0.y;
    o0.z = (v0.z - mu) * inv * g0.z + b0.z;
    o0.w = (v0.w - mu) * inv * g0.w + b0.w;
    o1.x = (v1.x - mu) * inv * g1.x + b1.x;
    o1.y = (v1.y - mu) * inv * g1.y + b1.y;
    o1.z = (v1.z - mu) * inv * g1.z + b1.z;
    o1.w = (v1.w - mu) * inv * g1.w + b1.w;
    *(float4*)(p + tid * 4) = o0;
    *(float4*)(p + 1024 + tid * 4) = o1;
}

extern "C" void kernel_launch(void* const* d_in, const int* in_sizes, int n_in,
                              void* d_out, int out_size, void* d_ws, size_t ws_size,
                              hipStream_t stream)
{
    const float* x     = (const float*)d_in[0];
    const float* Wi    = (const float*)d_in[1];
    const float* bias  = (const float*)d_in[2];
    const float* Wr    = (const float*)d_in[3];
    const float* mask  = (const float*)d_in[4];
    const float* tau   = (const float*)d_in[5];
    const float* gamma = (const float*)d_in[6];
    const float* beta  = (const float*)d_in[7];
    float* out = (float*)d_out;

    bf16_t* st0 = (bf16_t*)d_ws;
    bf16_t* st1 = st0 + (size_t)NBATCH * HID;
    int* flags  = (int*)(st1 + (size_t)NBATCH * HID);

    // 1) input projection -> d_out rows hold inp[b,t,:] (fp32); also zeroes flags
    gemm_proj<<<dim3(16, 64), 256, 0, stream>>>(x, Wi, bias, out, flags);
    // 2) persistent recurrence: overwrites d_out rows with pre-LN states
    recurrent<<<NBLK, RTHREADS, 0, stream>>>(Wr, mask, tau, out, st0, st1, flags);
    // 3) layernorm in-place
    ln_kernel<<<MTOT, 256, 0, stream>>>(out, gamma, beta);
}